// Round 8
// baseline (897.345 us; speedup 1.0000x reference)
//
#include <hip/hip_runtime.h>
#include <hip/hip_bf16.h>

#define H 4
#define D 256
#define NEG_SLOPE 0.2f

typedef __attribute__((ext_vector_type(8))) _Float16 f16x8;
typedef __attribute__((ext_vector_type(4))) _Float16 f16x4;
typedef __attribute__((ext_vector_type(4))) float f32x4;

// ---------------- f32 -> f16 convert (row-major, for W) ----------------
__global__ void k_cvt(const float* __restrict__ in, _Float16* __restrict__ out, int n4) {
    int i = blockIdx.x * blockDim.x + threadIdx.x;
    if (i >= n4) return;
    float4 v = ((const float4*)in)[i];
    f16x4 o = {(_Float16)v.x, (_Float16)v.y, (_Float16)v.z, (_Float16)v.w};
    *(f16x4*)&out[(size_t)i * 4] = o;
}

// ---- f32 x[N,128] -> 4 fp16 planes [4][Npad][32] ----
__global__ void k_cvt_x(const float* __restrict__ in, _Float16* __restrict__ xp,
                        size_t pstride, int n) {
    int i4 = blockIdx.x * blockDim.x + threadIdx.x;   // one float4 (4 cols)
    if (i4 >= n * 32) return;
    int row = i4 >> 5;
    int q   = i4 & 31;            // cols q*4..q*4+3
    float4 v = ((const float4*)in)[i4];
    f16x4 o = {(_Float16)v.x, (_Float16)v.y, (_Float16)v.z, (_Float16)v.w};
    int plane = q >> 3;
    int off   = (q & 7) * 4;
    *(f16x4*)&xp[(size_t)plane * pstride + (size_t)row * 32 + off] = o;
}

// ---- MFMA GEMM (fp16): h = x @ W^T from x planes; h planes, alpha [node][4] ----
template<int K>
__global__ __launch_bounds__(256) void k_gemm_mfma(
        const _Float16* __restrict__ xp, size_t xpstride,
        const _Float16* __restrict__ wf,
        const float* __restrict__ att_src, const float* __restrict__ att_dst,
        _Float16* __restrict__ hp, size_t hpstride,
        float* __restrict__ asp4, float* __restrict__ adp4,
        int nrows) {
    __shared__ _Float16 sx[64][40];
    __shared__ _Float16 sw[256][40];
    int t = threadIdx.x;
    int w = t >> 6, l = t & 63;
    int r = l & 15, q = l >> 4;
    int row0 = blockIdx.x * 64;
    f32x4 acc[16];
    #pragma unroll
    for (int cf = 0; cf < 16; ++cf) acc[cf] = (f32x4){0.f, 0.f, 0.f, 0.f};

    for (int k0 = 0; k0 < K; k0 += 32) {
        __syncthreads();
        // x tile: contiguous 4KB chunk of plane k0/32
        {
            const _Float16* xsrc = xp + (size_t)(k0 >> 5) * xpstride + (size_t)row0 * 32;
            uint4 v = *(const uint4*)(xsrc + (size_t)t * 8);
            *(uint4*)&sx[t >> 2][(t & 3) * 8] = v;
        }
        // W tile (256 x 32) from row-major [col][K]
        #pragma unroll
        for (int i = 0; i < 4; ++i) {
            int wr = (t >> 2) + i * 64;
            uint4 v = *(const uint4*)&wf[(size_t)wr * K + k0 + (t & 3) * 8];
            *(uint4*)&sw[wr][(t & 3) * 8] = v;
        }
        __syncthreads();
        f16x8 a = *(f16x8*)&sx[w * 16 + r][q * 8];
        #pragma unroll
        for (int cf = 0; cf < 16; ++cf) {
            f16x8 b = *(f16x8*)&sw[cf * 16 + r][q * 8];
            acc[cf] = __builtin_amdgcn_mfma_f32_16x16x32_f16(a, b, acc[cf], 0, 0, 0);
        }
    }
    // store h into planes: col=cf*16+r -> plane cf>>1, off (cf&1)*16+r
    #pragma unroll
    for (int cf = 0; cf < 16; ++cf) {
        _Float16* hpl = hp + (size_t)(cf >> 1) * hpstride;
        #pragma unroll
        for (int i = 0; i < 4; ++i) {
            int gr = row0 + w * 16 + q * 4 + i;
            if (gr < nrows)
                hpl[(size_t)gr * 32 + (cf & 1) * 16 + r] = (_Float16)acc[cf][i];
        }
    }
    // fused alpha epilogue -> [node][4] (float4-friendly)
    float asv[16], adv[16];
    #pragma unroll
    for (int cf = 0; cf < 16; ++cf) {
        asv[cf] = att_src[cf * 16 + r];
        adv[cf] = att_dst[cf * 16 + r];
    }
    #pragma unroll
    for (int i = 0; i < 4; ++i) {
        #pragma unroll
        for (int h4 = 0; h4 < 4; ++h4) {
            float ps = 0.f, pd = 0.f;
            #pragma unroll
            for (int j = 0; j < 4; ++j) {
                int cf = h4 * 4 + j;
                ps += acc[cf][i] * asv[cf];
                pd += acc[cf][i] * adv[cf];
            }
            #pragma unroll
            for (int m = 1; m < 16; m <<= 1) {
                ps += __shfl_xor(ps, m);
                pd += __shfl_xor(pd, m);
            }
            int gr = row0 + w * 16 + q * 4 + i;
            if (r == 0 && gr < nrows) {
                asp4[(size_t)gr * 4 + h4] = ps;
                adp4[(size_t)gr * 4 + h4] = pd;
            }
        }
    }
}

// ---------------- CSR build (graph constant across layers) ----------------
__global__ void k_deg(const int* __restrict__ ei, int E, int E2, int* __restrict__ deg) {
    int e = blockIdx.x * blockDim.x + threadIdx.x;
    if (e >= E2) return;
    int de = (e < E) ? ei[E + e] : (e - E);
    atomicAdd(&deg[de], 1);
}

__global__ void k_scan_block(const int* __restrict__ deg, int* __restrict__ incl,
                             int* __restrict__ bsum, int n) {
    __shared__ int sd[256];
    int t = threadIdx.x;
    int i = blockIdx.x * 256 + t;
    int v = (i < n) ? deg[i] : 0;
    sd[t] = v;
    __syncthreads();
    for (int off = 1; off < 256; off <<= 1) {
        int add = (t >= off) ? sd[t - off] : 0;
        __syncthreads();
        sd[t] += add;
        __syncthreads();
    }
    if (i < n) incl[i] = sd[t];
    if (t == 255) bsum[blockIdx.x] = sd[255];
}

__global__ void k_scan_bsum(int* __restrict__ bsum, int nb) {
    __shared__ int sd[256];
    int t = threadIdx.x;
    int v = (t < nb) ? bsum[t] : 0;
    sd[t] = v;
    __syncthreads();
    for (int off = 1; off < 256; off <<= 1) {
        int add = (t >= off) ? sd[t - off] : 0;
        __syncthreads();
        sd[t] += add;
        __syncthreads();
    }
    if (t < nb) bsum[t] = sd[t] - v;
}

__global__ void k_rowptr(const int* __restrict__ incl, const int* __restrict__ deg,
                         const int* __restrict__ boff, int* __restrict__ row_ptr,
                         int n, int total) {
    int i = blockIdx.x * blockDim.x + threadIdx.x;
    if (i < n) row_ptr[i] = incl[i] - deg[i] + boff[i >> 8];
    if (i == 0) row_ptr[n] = total;
}

__global__ void k_scatter(const int* __restrict__ ei, int E, int E2,
                          const int* __restrict__ row_ptr, int* __restrict__ cursor,
                          int* __restrict__ csr_src) {
    int e = blockIdx.x * blockDim.x + threadIdx.x;
    if (e >= E2) return;
    int se, de;
    if (e < E) { se = ei[e]; de = ei[E + e]; }
    else       { se = e - E; de = se; }
    int pos = atomicAdd(&cursor[de], 1);
    csr_src[row_ptr[de] + pos] = se;
}

// ---- per-node: edge weights for all 4 heads (CSR order, [E2][4]) + sums ----
__global__ void k_edge(const int* __restrict__ row_ptr, const int* __restrict__ csr_src,
                       const float4* __restrict__ asp4, const float4* __restrict__ adp4,
                       float4* __restrict__ ew4, float4* __restrict__ sp4, int n) {
    int node = blockIdx.x * blockDim.x + threadIdx.x;
    if (node >= n) return;
    float4 ad = adp4[node];
    int st = row_ptr[node], en = row_ptr[node + 1];
    float4 s = make_float4(0.f, 0.f, 0.f, 0.f);
    for (int i = st; i < en; ++i) {
        float4 as = asp4[csr_src[i]];
        float4 w;
        float a;
        a = as.x + ad.x; a = a > 0.f ? a : NEG_SLOPE * a; w.x = __expf(a);
        a = as.y + ad.y; a = a > 0.f ? a : NEG_SLOPE * a; w.y = __expf(a);
        a = as.z + ad.z; a = a > 0.f ? a : NEG_SLOPE * a; w.z = __expf(a);
        a = as.w + ad.w; a = a > 0.f ? a : NEG_SLOPE * a; w.w = __expf(a);
        ew4[i] = w;
        s.x += w.x; s.y += w.y; s.z += w.z; s.w += w.w;
    }
    sp4[node] = s;
}

// ---- aggregation v4: channel-sliced XCD-affine, wave per node, vector gather ----
// lane = (e8 = lane>>3 edge slot, c8 = lane&7 channel quad). 3 VMEM / 8 edges.
__global__ __launch_bounds__(256) void k_aggregate4(
        const _Float16* __restrict__ hp, size_t hpstride,
        const int* __restrict__ row_ptr, const int* __restrict__ csr_src,
        const float* __restrict__ ew4, const float* __restrict__ sp4,
        const float* __restrict__ bias, float* __restrict__ outf,
        _Float16* __restrict__ outx, size_t xpstride,
        int relu, int nrows) {
    int bid = blockIdx.x;
    int cg = bid & 7;                      // channel group -> XCD (round-robin)
    int node = (bid >> 3) * 4 + (threadIdx.x >> 6);
    if (node >= nrows) return;
    int lane = threadIdx.x & 63;
    int e8 = lane >> 3;
    int c8 = lane & 7;
    int head = cg >> 1;
    const _Float16* hpl = hp + (size_t)cg * hpstride;
    int st = row_ptr[node], en = row_ptr[node + 1];
    int deg = en - st;
    f32x4 acc = (f32x4){0.f, 0.f, 0.f, 0.f};
    for (int b = 0; b < deg; b += 8) {
        int e = b + e8;
        int li = st + (e < deg ? e : deg - 1);
        int sn = csr_src[li];
        float w = (e < deg) ? ew4[(size_t)li * 4 + head] : 0.f;
        f16x4 hv = *(const f16x4*)&hpl[(size_t)sn * 32 + c8 * 4];
        acc[0] += w * (float)hv[0];
        acc[1] += w * (float)hv[1];
        acc[2] += w * (float)hv[2];
        acc[3] += w * (float)hv[3];
    }
    // reduce over the 8 edge slots (lane bits 3..5)
    #pragma unroll
    for (int m = 8; m < 64; m <<= 1) {
        acc[0] += __shfl_xor(acc[0], m);
        acc[1] += __shfl_xor(acc[1], m);
        acc[2] += __shfl_xor(acc[2], m);
        acc[3] += __shfl_xor(acc[3], m);
    }
    if (e8 == 0) {
        float sinv = 1.f / (sp4[(size_t)node * 4 + head] + 1e-16f);
        float o[4];
        #pragma unroll
        for (int j = 0; j < 4; ++j) {
            o[j] = acc[j] * sinv + bias[cg * 32 + c8 * 4 + j];
            if (relu) o[j] = fmaxf(o[j], 0.f);
        }
        if (outx) {
            f16x4 o4 = {(_Float16)o[0], (_Float16)o[1], (_Float16)o[2], (_Float16)o[3]};
            *(f16x4*)&outx[(size_t)cg * xpstride + (size_t)node * 32 + c8 * 4] = o4;
        } else {
            *(float4*)&outf[(size_t)node * 256 + cg * 32 + c8 * 4] =
                make_float4(o[0], o[1], o[2], o[3]);
        }
    }
}

extern "C" void kernel_launch(void* const* d_in, const int* in_sizes, int n_in,
                              void* d_out, int out_size, void* d_ws, size_t ws_size,
                              hipStream_t stream) {
    const float* x = (const float*)d_in[0];
    const int* ei = (const int*)d_in[1];
    const int N  = in_sizes[0] / 128;   // 50000
    const int E  = in_sizes[1] / 2;     // 400000
    const int E2 = E + N;               // + self loops
    const int Npad = (N + 63) & ~63;    // 50048
    const size_t PST = (size_t)Npad * 32;   // fp16 plane stride (elems)

    char* wsp = (char*)d_ws;
    size_t off = 0;
    auto alloc = [&](size_t bytes) -> void* {
        void* p = wsp + off;
        off += (bytes + 255) & ~(size_t)255;
        return p;
    };
    _Float16* xp   = (_Float16*)alloc(8 * PST * 2);        // x planes (25.6 MB)
    _Float16* hp   = (_Float16*)alloc(8 * PST * 2);        // h planes (25.6 MB)
    _Float16* wf16 = (_Float16*)alloc((size_t)5 * D * D * 2);
    float* asp4 = (float*)alloc((size_t)Npad * 4 * 4);
    float* adp4 = (float*)alloc((size_t)Npad * 4 * 4);
    float* sp4  = (float*)alloc((size_t)Npad * 4 * 4);
    float* ew4  = (float*)alloc((size_t)E2 * 4 * 4);       // 7.2 MB
    int* deg     = (int*)alloc((size_t)N * 4);
    int* incl    = (int*)alloc((size_t)N * 4);
    int* bsum    = (int*)alloc(256 * 4);
    int* row_ptr = (int*)alloc((size_t)(N + 1) * 4);
    int* cursor  = (int*)alloc((size_t)N * 4);
    int* csr_src = (int*)alloc((size_t)E2 * 4);
    (void)ws_size;

    hipMemsetAsync(deg, 0, (size_t)N * 4, stream);
    hipMemsetAsync(cursor, 0, (size_t)N * 4, stream);

    // convert x -> 4 planes; W -> fp16 row-major
    int nx4 = N * 32;
    k_cvt_x<<<(nx4 + 255) / 256, 256, 0, stream>>>(x, xp, PST, N);
    for (int l = 0; l < 5; ++l) {
        const float* W = (const float*)d_in[2 + 4 * l];
        int nw4 = D * (l == 0 ? 128 : 256) / 4;
        k_cvt<<<(nw4 + 255) / 256, 256, 0, stream>>>(W, wf16 + (size_t)l * D * D, nw4);
    }

    // CSR by dst
    int egrid = (E2 + 255) / 256;
    k_deg<<<egrid, 256, 0, stream>>>(ei, E, E2, deg);
    int nb = (N + 255) / 256;
    k_scan_block<<<nb, 256, 0, stream>>>(deg, incl, bsum, N);
    k_scan_bsum<<<1, 256, 0, stream>>>(bsum, nb);
    k_rowptr<<<nb, 256, 0, stream>>>(incl, deg, bsum, row_ptr, N, E2);
    k_scatter<<<egrid, 256, 0, stream>>>(ei, E, E2, row_ptr, cursor, csr_src);

    int ggrid = (N + 63) / 64;
    int agrid = ((N + 3) / 4) * 8;                 // node-chunks x 8 channel-groups
    int ngrid = (N + 255) / 256;
    for (int l = 0; l < 5; ++l) {
        const float* as_ = (const float*)d_in[3 + 4 * l];
        const float* ad_ = (const float*)d_in[4 + 4 * l];
        const float* bs_ = (const float*)d_in[5 + 4 * l];
        const _Float16* wl = wf16 + (size_t)l * D * D;

        if (l == 0)
            k_gemm_mfma<128><<<ggrid, 256, 0, stream>>>(xp, PST, wl, as_, ad_,
                                                        hp, PST, asp4, adp4, N);
        else
            k_gemm_mfma<256><<<ggrid, 256, 0, stream>>>(xp, PST, wl, as_, ad_,
                                                        hp, PST, asp4, adp4, N);

        k_edge<<<ngrid, 256, 0, stream>>>(row_ptr, csr_src, (const float4*)asp4,
                                          (const float4*)adp4, (float4*)ew4,
                                          (float4*)sp4, N);

        int last = (l == 4);
        k_aggregate4<<<agrid, 256, 0, stream>>>(hp, PST, row_ptr, csr_src, ew4, sp4,
                                                bs_, last ? (float*)d_out : nullptr,
                                                last ? nullptr : xp, PST,
                                                last ? 0 : 1, N);
    }
}

// Round 9
// 429.985 us; speedup vs baseline: 2.0869x; 2.0869x over previous
//
#include <hip/hip_runtime.h>
#include <hip/hip_bf16.h>

#define H 4
#define D 256
#define NEG_SLOPE 0.2f

typedef __attribute__((ext_vector_type(8))) _Float16 f16x8;
typedef __attribute__((ext_vector_type(4))) _Float16 f16x4;
typedef __attribute__((ext_vector_type(4))) float f32x4;

// ---- merged f32->f16 convert: x[N,128] + W0[128*256] + W1..4[256*256] ----
__global__ void k_cvt_all(const float* __restrict__ x,
                          const float* __restrict__ w0, const float* __restrict__ w1,
                          const float* __restrict__ w2, const float* __restrict__ w3,
                          const float* __restrict__ w4,
                          _Float16* __restrict__ xf, _Float16* __restrict__ wf,
                          int nx4) {
    int i = blockIdx.x * blockDim.x + threadIdx.x;
    const int nW0 = 128 * 256 / 4, nW = 256 * 256 / 4;
    const float* src;
    _Float16* dst;
    int off;
    if (i < nx4) { src = x; dst = xf; off = i; }
    else {
        i -= nx4;
        if (i < nW0) { src = w0; dst = wf; off = i; }
        else {
            i -= nW0;
            int l = i / nW, r2 = i % nW;
            if (l >= 4) return;
            const float* ws[4] = {w1, w2, w3, w4};
            src = ws[l];
            dst = wf + 128 * 256 + (size_t)l * 256 * 256;
            off = r2;
        }
    }
    float4 v = ((const float4*)src)[off];
    f16x4 o = {(_Float16)v.x, (_Float16)v.y, (_Float16)v.z, (_Float16)v.w};
    *(f16x4*)&dst[(size_t)off * 4] = o;
}

// ---- MFMA GEMM (fp16): h[N,256] = x[N,K] @ W[256,K]^T, fused alpha ----
template<int K>
__global__ __launch_bounds__(256) void k_gemm_mfma(
        const _Float16* __restrict__ xf, const _Float16* __restrict__ wf,
        const float* __restrict__ att_src, const float* __restrict__ att_dst,
        _Float16* __restrict__ hmat, float* __restrict__ alpha_src,
        float* __restrict__ alpha_dst, int nrows) {
    __shared__ _Float16 sx[64][40];
    __shared__ _Float16 sw[256][40];
    int t = threadIdx.x;
    int w = t >> 6, l = t & 63;
    int r = l & 15, q = l >> 4;
    int row0 = blockIdx.x * 64;
    f32x4 acc[16];
    #pragma unroll
    for (int cf = 0; cf < 16; ++cf) acc[cf] = (f32x4){0.f, 0.f, 0.f, 0.f};

    for (int k0 = 0; k0 < K; k0 += 32) {
        __syncthreads();
        {
            int gr = row0 + (t >> 2);
            uint4 v = make_uint4(0, 0, 0, 0);
            if (gr < nrows) v = *(const uint4*)&xf[(size_t)gr * K + k0 + (t & 3) * 8];
            *(uint4*)&sx[t >> 2][(t & 3) * 8] = v;
        }
        #pragma unroll
        for (int i = 0; i < 4; ++i) {
            int wr = (t >> 2) + i * 64;
            uint4 v = *(const uint4*)&wf[(size_t)wr * K + k0 + (t & 3) * 8];
            *(uint4*)&sw[wr][(t & 3) * 8] = v;
        }
        __syncthreads();
        f16x8 a = *(f16x8*)&sx[w * 16 + r][q * 8];
        #pragma unroll
        for (int cf = 0; cf < 16; ++cf) {
            f16x8 b = *(f16x8*)&sw[cf * 16 + r][q * 8];
            acc[cf] = __builtin_amdgcn_mfma_f32_16x16x32_f16(a, b, acc[cf], 0, 0, 0);
        }
    }
    // store h (fp16): D[row=(q*4+i)][col=cf*16+r]
    #pragma unroll
    for (int cf = 0; cf < 16; ++cf) {
        #pragma unroll
        for (int i = 0; i < 4; ++i) {
            int gr = row0 + w * 16 + q * 4 + i;
            if (gr < nrows) hmat[(size_t)gr * D + cf * 16 + r] = (_Float16)acc[cf][i];
        }
    }
    // fused alpha epilogue -> [node*4 + head]
    float asv[16], adv[16];
    #pragma unroll
    for (int cf = 0; cf < 16; ++cf) {
        asv[cf] = att_src[cf * 16 + r];
        adv[cf] = att_dst[cf * 16 + r];
    }
    #pragma unroll
    for (int i = 0; i < 4; ++i) {
        #pragma unroll
        for (int h4 = 0; h4 < 4; ++h4) {
            float ps = 0.f, pd = 0.f;
            #pragma unroll
            for (int j = 0; j < 4; ++j) {
                int cf = h4 * 4 + j;
                ps += acc[cf][i] * asv[cf];
                pd += acc[cf][i] * adv[cf];
            }
            #pragma unroll
            for (int m = 1; m < 16; m <<= 1) {
                ps += __shfl_xor(ps, m);
                pd += __shfl_xor(pd, m);
            }
            int gr = row0 + w * 16 + q * 4 + i;
            if (r == 0 && gr < nrows) {
                alpha_src[gr * 4 + h4] = ps;
                alpha_dst[gr * 4 + h4] = pd;
            }
        }
    }
}

// ---------------- CSR build (graph constant across layers) ----------------
__global__ void k_deg(const int* __restrict__ ei, int E, int E2, int* __restrict__ deg) {
    int e = blockIdx.x * blockDim.x + threadIdx.x;
    if (e >= E2) return;
    int de = (e < E) ? ei[E + e] : (e - E);
    atomicAdd(&deg[de], 1);
}

__global__ void k_scan_block(const int* __restrict__ deg, int* __restrict__ incl,
                             int* __restrict__ bsum, int n) {
    __shared__ int sd[256];
    int t = threadIdx.x;
    int i = blockIdx.x * 256 + t;
    int v = (i < n) ? deg[i] : 0;
    sd[t] = v;
    __syncthreads();
    for (int off = 1; off < 256; off <<= 1) {
        int add = (t >= off) ? sd[t - off] : 0;
        __syncthreads();
        sd[t] += add;
        __syncthreads();
    }
    if (i < n) incl[i] = sd[t];
    if (t == 255) bsum[blockIdx.x] = sd[255];
}

__global__ void k_scan_bsum(int* __restrict__ bsum, int nb) {
    __shared__ int sd[256];
    int t = threadIdx.x;
    int v = (t < nb) ? bsum[t] : 0;
    sd[t] = v;
    __syncthreads();
    for (int off = 1; off < 256; off <<= 1) {
        int add = (t >= off) ? sd[t - off] : 0;
        __syncthreads();
        sd[t] += add;
        __syncthreads();
    }
    if (t < nb) bsum[t] = sd[t] - v;
}

__global__ void k_rowptr(const int* __restrict__ incl, const int* __restrict__ deg,
                         const int* __restrict__ boff, int* __restrict__ row_ptr,
                         int n, int total) {
    int i = blockIdx.x * blockDim.x + threadIdx.x;
    if (i < n) row_ptr[i] = incl[i] - deg[i] + boff[i >> 8];
    if (i == 0) row_ptr[n] = total;
}

__global__ void k_scatter(const int* __restrict__ ei, int E, int E2,
                          const int* __restrict__ row_ptr, int* __restrict__ cursor,
                          int* __restrict__ csr_src) {
    int e = blockIdx.x * blockDim.x + threadIdx.x;
    if (e >= E2) return;
    int se, de;
    if (e < E) { se = ei[e]; de = ei[E + e]; }
    else       { se = e - E; de = se; }
    int pos = atomicAdd(&cursor[de], 1);
    csr_src[row_ptr[de] + pos] = se;
}

// ---- aggregation: wave per node; lane=(e2,c); 16 edges in flight; f16x8 ----
__global__ __launch_bounds__(256) void k_aggregate(const _Float16* __restrict__ hmat,
        const int* __restrict__ row_ptr, const int* __restrict__ csr_src,
        const float* __restrict__ alpha_src, const float* __restrict__ alpha_dst,
        const float* __restrict__ bias, float* __restrict__ outf,
        _Float16* __restrict__ outx, int relu, int nrows) {
    int node = (blockIdx.x * 256 + threadIdx.x) >> 6;
    if (node >= nrows) return;
    int lane = threadIdx.x & 63;
    int e2 = lane >> 5;            // edge-slot half (0/1)
    int c  = lane & 31;            // channel octet: channels c*8..c*8+7
    int head = c >> 3;
    int st = row_ptr[node], en = row_ptr[node + 1];
    int deg = en - st;
    float a_d = alpha_dst[node * 4 + head];
    float acc[8] = {};
    float ssum = 0.f;
    for (int b = 0; b < deg; b += 16) {
        int sn[8];
        #pragma unroll
        for (int j = 0; j < 8; ++j) {
            int e = b + e2 * 8 + j;
            int li = st + (e < deg ? e : deg - 1);
            sn[j] = csr_src[li];
        }
        f16x8 hv[8];
        #pragma unroll
        for (int j = 0; j < 8; ++j)
            hv[j] = *(const f16x8*)&hmat[(size_t)sn[j] * D + c * 8];
        float as[8];
        #pragma unroll
        for (int j = 0; j < 8; ++j) as[j] = alpha_src[sn[j] * 4 + head];
        #pragma unroll
        for (int j = 0; j < 8; ++j) {
            int e = b + e2 * 8 + j;
            float a = as[j] + a_d;
            a = a > 0.f ? a : NEG_SLOPE * a;
            float ex = (e < deg) ? __expf(a) : 0.f;
            ssum += ex;
            #pragma unroll
            for (int k = 0; k < 8; ++k) acc[k] += ex * (float)hv[j][k];
        }
    }
    ssum += __shfl_xor(ssum, 32);
    #pragma unroll
    for (int k = 0; k < 8; ++k) acc[k] += __shfl_xor(acc[k], 32);
    if (e2 == 0) {
        float sinv = 1.f / (ssum + 1e-16f);
        float4 b0 = *(const float4*)&bias[c * 8];
        float4 b1 = *(const float4*)&bias[c * 8 + 4];
        float o[8];
        o[0] = acc[0] * sinv + b0.x; o[1] = acc[1] * sinv + b0.y;
        o[2] = acc[2] * sinv + b0.z; o[3] = acc[3] * sinv + b0.w;
        o[4] = acc[4] * sinv + b1.x; o[5] = acc[5] * sinv + b1.y;
        o[6] = acc[6] * sinv + b1.z; o[7] = acc[7] * sinv + b1.w;
        if (relu) {
            #pragma unroll
            for (int k = 0; k < 8; ++k) o[k] = fmaxf(o[k], 0.f);
        }
        if (outx) {
            f16x8 o8 = {(_Float16)o[0], (_Float16)o[1], (_Float16)o[2], (_Float16)o[3],
                        (_Float16)o[4], (_Float16)o[5], (_Float16)o[6], (_Float16)o[7]};
            *(f16x8*)&outx[(size_t)node * D + c * 8] = o8;
        } else {
            *(float4*)&outf[(size_t)node * D + c * 8] =
                make_float4(o[0], o[1], o[2], o[3]);
            *(float4*)&outf[(size_t)node * D + c * 8 + 4] =
                make_float4(o[4], o[5], o[6], o[7]);
        }
    }
}

extern "C" void kernel_launch(void* const* d_in, const int* in_sizes, int n_in,
                              void* d_out, int out_size, void* d_ws, size_t ws_size,
                              hipStream_t stream) {
    const float* x = (const float*)d_in[0];
    const int* ei = (const int*)d_in[1];
    const int N  = in_sizes[0] / 128;   // 50000
    const int E  = in_sizes[1] / 2;     // 400000
    const int E2 = E + N;               // + self loops

    char* wsp = (char*)d_ws;
    size_t off = 0;
    auto alloc = [&](size_t bytes) -> void* {
        void* p = wsp + off;
        off += (bytes + 255) & ~(size_t)255;
        return p;
    };
    _Float16* bufH  = (_Float16*)alloc((size_t)N * D * 2);     // 25.6 MB
    _Float16* xf16  = (_Float16*)alloc((size_t)N * D * 2);     // 25.6 MB
    _Float16* wf16  = (_Float16*)alloc((size_t)(128 * 256 + 4 * 256 * 256) * 2);
    float* alpha_src = (float*)alloc((size_t)N * H * 4);
    float* alpha_dst = (float*)alloc((size_t)N * H * 4);
    int*   deg       = (int*)alloc((size_t)N * 4);
    int*   incl      = (int*)alloc((size_t)N * 4);
    int*   bsum      = (int*)alloc(256 * 4);
    int*   row_ptr   = (int*)alloc((size_t)(N + 1) * 4);
    int*   cursor    = (int*)alloc((size_t)N * 4);
    int*   csr_src   = (int*)alloc((size_t)E2 * 4);
    (void)ws_size;

    hipMemsetAsync(deg, 0, (size_t)N * 4, stream);
    hipMemsetAsync(cursor, 0, (size_t)N * 4, stream);

    // merged convert: x + all 5 W
    int nx4 = N * 128 / 4;
    int tot4 = nx4 + 128 * 256 / 4 + 4 * (256 * 256 / 4);
    k_cvt_all<<<(tot4 + 255) / 256, 256, 0, stream>>>(
        x, (const float*)d_in[2], (const float*)d_in[6], (const float*)d_in[10],
        (const float*)d_in[14], (const float*)d_in[18], xf16, wf16, nx4);

    // CSR by dst
    int egrid = (E2 + 255) / 256;
    k_deg<<<egrid, 256, 0, stream>>>(ei, E, E2, deg);
    int nb = (N + 255) / 256;
    k_scan_block<<<nb, 256, 0, stream>>>(deg, incl, bsum, N);
    k_scan_bsum<<<1, 256, 0, stream>>>(bsum, nb);
    k_rowptr<<<nb, 256, 0, stream>>>(incl, deg, bsum, row_ptr, N, E2);
    k_scatter<<<egrid, 256, 0, stream>>>(ei, E, E2, row_ptr, cursor, csr_src);

    int ggrid = (N + 63) / 64;
    int agrid = (N + 3) / 4;
    for (int l = 0; l < 5; ++l) {
        const float* as_ = (const float*)d_in[3 + 4 * l];
        const float* ad_ = (const float*)d_in[4 + 4 * l];
        const float* bs_ = (const float*)d_in[5 + 4 * l];
        const _Float16* wl = (l == 0) ? wf16
                           : wf16 + 128 * 256 + (size_t)(l - 1) * 256 * 256;

        if (l == 0)
            k_gemm_mfma<128><<<ggrid, 256, 0, stream>>>(xf16, wl, as_, ad_,
                                                        bufH, alpha_src, alpha_dst, N);
        else
            k_gemm_mfma<256><<<ggrid, 256, 0, stream>>>(xf16, wl, as_, ad_,
                                                        bufH, alpha_src, alpha_dst, N);

        int last = (l == 4);
        k_aggregate<<<agrid, 256, 0, stream>>>(bufH, row_ptr, csr_src,
                                               alpha_src, alpha_dst, bs_,
                                               last ? (float*)d_out : nullptr,
                                               last ? nullptr : xf16,
                                               last ? 0 : 1, N);
    }
}